// Round 2
// baseline (642.301 us; speedup 1.0000x reference)
//
#include <hip/hip_runtime.h>
#include <math.h>

#define BB  8
#define NN  262144
#define GG  64
#define NBG (BB * GG)      // 512
#define TOT (BB * NN)      // 2097152

// ws float layout:
//   [0    ..  512) zsumP
//   [512  .. 1024) zsumT
//   [1024 .. 1536) cnt
//   [1536 .. 2048) invP  (1/max(|mean_pred|,eps))
//   [2048 .. 2560) invT
//   [2560]         nvalid (float)
//   float idx 2688 (byte 10752, 8-aligned): double acc[6]
//     acc: {s3d, s2d, svis, sdisp, snorm, sconf}
#define WS_ACC_F 2688
#define WS_BYTES (WS_ACC_F * 4 + 6 * 8)

__device__ __forceinline__ float wred(float v) {
#pragma unroll
    for (int o = 32; o > 0; o >>= 1) v += __shfl_down(v, o, 64);
    return v;
}

// ---- Kernel 1: per-(b,g) z sums + counts. 1024 blocks x 256 thr, chunk=2048 (one b per block)
__global__ __launch_bounds__(256) void k_group(const float* __restrict__ pp,
                                               const float* __restrict__ tp,
                                               const int* __restrict__ mask,
                                               const int* __restrict__ grp,
                                               float* __restrict__ ws) {
    __shared__ float sP[GG], sT[GG], sC[GG];
    if (threadIdx.x < GG) { sP[threadIdx.x] = 0.f; sT[threadIdx.x] = 0.f; sC[threadIdx.x] = 0.f; }
    __syncthreads();

    const int base = blockIdx.x * 2048;           // 2048 | NN so one batch per block
    const int b = base >> 18;                     // i / NN
#pragma unroll
    for (int j = 0; j < 2048; j += 256) {
        int i = base + j + threadIdx.x;
        if (mask[i]) {
            int g = grp[i];
            atomicAdd(&sP[g], pp[i * 3 + 2]);
            atomicAdd(&sT[g], tp[i * 3 + 2]);
            atomicAdd(&sC[g], 1.0f);
        }
    }
    __syncthreads();
    if (threadIdx.x < GG) {
        float c = sC[threadIdx.x];
        if (c != 0.0f) {
            int e = b * GG + threadIdx.x;
            atomicAdd(&ws[e], sP[threadIdx.x]);
            atomicAdd(&ws[NBG + e], sT[threadIdx.x]);
            atomicAdd(&ws[2 * NBG + e], c);
        }
    }
}

// ---- Kernel 2: finalize inverse safe means + total valid count. 1 block x 512 thr
__global__ __launch_bounds__(512) void k_groups_final(float* __restrict__ ws) {
    __shared__ float red[NBG];
    int j = threadIdx.x;
    float c = ws[2 * NBG + j];
    float mP = (c > 0.f) ? (ws[j] / fmaxf(c, 1.f)) : 1.0f;
    float mT = (c > 0.f) ? (ws[NBG + j] / fmaxf(c, 1.f)) : 1.0f;
    ws[3 * NBG + j] = 1.0f / fmaxf(fabsf(mP), 1e-6f);
    ws[4 * NBG + j] = 1.0f / fmaxf(fabsf(mT), 1e-6f);
    red[j] = c;
    __syncthreads();
    for (int s = 256; s > 0; s >>= 1) {
        if (j < s) red[j] += red[j + s];
        __syncthreads();
    }
    if (j == 0) ws[5 * NBG] = red[0];
}

// ---- Kernel 3: main loss pass. 2048 blocks x 256 thr, chunk=1024
__global__ __launch_bounds__(256) void k_loss(const float* __restrict__ pp,
                                              const float* __restrict__ tp,
                                              const float* __restrict__ p2,
                                              const float* __restrict__ t2,
                                              const float* __restrict__ pv,
                                              const float* __restrict__ tv,
                                              const float* __restrict__ pd,
                                              const float* __restrict__ td,
                                              const float* __restrict__ pn,
                                              const float* __restrict__ tn,
                                              const float* __restrict__ cf,
                                              const int* __restrict__ mask,
                                              const int* __restrict__ grp,
                                              float* __restrict__ ws) {
    const float* invP = ws + 3 * NBG;
    const float* invT = ws + 4 * NBG;
    double* acc = (double*)(ws + WS_ACC_F);

    float s3d = 0.f, s2 = 0.f, sv = 0.f, sd = 0.f, sn = 0.f, sc = 0.f;

    const int base = blockIdx.x * 1024;
#pragma unroll
    for (int j = 0; j < 1024; j += 256) {
        int i = base + j + threadIdx.x;
        if (!mask[i]) continue;
        int e = ((i >> 18) << 6) | grp[i];
        float iP = invP[e], iT = invT[e];
        int i3 = i * 3;
        int i2 = i * 2;

        // L_3D: normalize by group mean depth, log-transform, L1
#pragma unroll
        for (int k = 0; k < 3; k++) {
            float a = pp[i3 + k] * iP;
            float b2 = tp[i3 + k] * iT;
            float la = copysignf(log1pf(fabsf(a)), a);
            float lb = copysignf(log1pf(fabsf(b2)), b2);
            s3d += fabsf(la - lb);
        }
        // L_2D
        s2 += fabsf(p2[i2] - t2[i2]) + fabsf(p2[i2 + 1] - t2[i2 + 1]);
        // L_vis (BCE with logits)
        {
            float x = pv[i], t = tv[i];
            sv += fmaxf(x, 0.f) - x * t + log1pf(expf(-fabsf(x)));
        }
        // L_disp
        sd += fabsf(pd[i3] - td[i3]) + fabsf(pd[i3 + 1] - td[i3 + 1]) + fabsf(pd[i3 + 2] - td[i3 + 2]);
        // L_normal: 1 - cos
        {
            float ax = pn[i3], ay = pn[i3 + 1], az = pn[i3 + 2];
            float bx = tn[i3], by = tn[i3 + 1], bz = tn[i3 + 2];
            float na = fmaxf(sqrtf(ax * ax + ay * ay + az * az), 1e-12f);
            float nb = fmaxf(sqrtf(bx * bx + by * by + bz * bz), 1e-12f);
            sn += 1.0f - (ax * bx + ay * by + az * bz) / (na * nb);
        }
        // L_conf
        sc += cf[i];
    }

    float vals[6] = {s3d, s2, sv, sd, sn, sc};
    int lane = threadIdx.x & 63;
#pragma unroll
    for (int k = 0; k < 6; k++) {
        float r = wred(vals[k]);
        if (lane == 0) atomicAdd(&acc[k], (double)r);
    }
}

// ---- Kernel 4: combine
__global__ void k_combine(const float* __restrict__ ws, float* __restrict__ out) {
    const double* acc = (const double*)(ws + WS_ACC_F);
    double nv = (double)ws[5 * NBG];
    double d1 = nv + 1e-6;
    double d3 = 3.0 * nv + 1e-6;
    double l3d   = acc[0] / d3;
    double l2d   = acc[1] / (2.0 * nv + 1e-6);
    double lvis  = acc[2] / d1;
    double ldisp = acc[3] / d3;   // disp is (B,N,3): mask broadcasts to 3 channels
    double lnorm = acc[4] / d1;
    double lconf = acc[5] / d1;
    out[0] = (float)(l3d + 0.1 * (l2d + lvis + ldisp) + 0.5 * lnorm + 0.2 * lconf);
}

extern "C" void kernel_launch(void* const* d_in, const int* in_sizes, int n_in,
                              void* d_out, int out_size, void* d_ws, size_t ws_size,
                              hipStream_t stream) {
    const float* pp = (const float*)d_in[0];
    const float* tp = (const float*)d_in[1];
    const float* p2 = (const float*)d_in[2];
    const float* t2 = (const float*)d_in[3];
    const float* pv = (const float*)d_in[4];
    const float* tv = (const float*)d_in[5];
    const float* pd = (const float*)d_in[6];
    const float* td = (const float*)d_in[7];
    const float* pn = (const float*)d_in[8];
    const float* tn = (const float*)d_in[9];
    const float* cf = (const float*)d_in[10];
    const int* mask = (const int*)d_in[11];
    const int* grp  = (const int*)d_in[12];
    float* ws = (float*)d_ws;
    float* out = (float*)d_out;

    hipMemsetAsync(d_ws, 0, WS_BYTES, stream);
    k_group<<<TOT / 2048, 256, 0, stream>>>(pp, tp, mask, grp, ws);
    k_groups_final<<<1, NBG, 0, stream>>>(ws);
    k_loss<<<TOT / 1024, 256, 0, stream>>>(pp, tp, p2, t2, pv, tv, pd, td, pn, tn, cf, mask, grp, ws);
    k_combine<<<1, 1, 0, stream>>>(ws, out);
}

// Round 3
// 82.804 us; speedup vs baseline: 7.7569x; 7.7569x over previous
//
#include <hip/hip_runtime.h>
#include <math.h>

#define BB  8
#define NN  262144
#define GG  64
#define NBG (BB * GG)      // 512
#define TOT (BB * NN)      // 2097152
#define NBLK 2048          // k_loss blocks

// ws float layout:
//   [0    ..  512) zsumP
//   [512  .. 1024) zsumT
//   [1024 .. 1536) cnt
//   [1536 .. 2048) invP  (1/max(|mean_pred|,eps))
//   [2048 .. 2560) invT
//   [2560]         nvalid (float)
//   [4096 .. 4096+6*2048) per-block partials, transposed: partials[k*2048+blk]
#define PART_F 4096
#define WS_ZERO_BYTES (3 * NBG * 4)   // only the atomic-accumulated region

__device__ __forceinline__ float wredf(float v) {
#pragma unroll
    for (int o = 32; o > 0; o >>= 1) v += __shfl_down(v, o, 64);
    return v;
}

// ---- Kernel 1: per-(b,g) z sums + counts. 1024 blocks x 256 thr, chunk=2048 (one b per block)
__global__ __launch_bounds__(256) void k_group(const float* __restrict__ pp,
                                               const float* __restrict__ tp,
                                               const int* __restrict__ mask,
                                               const int* __restrict__ grp,
                                               float* __restrict__ ws) {
    __shared__ float sP[GG], sT[GG], sC[GG];
    if (threadIdx.x < GG) { sP[threadIdx.x] = 0.f; sT[threadIdx.x] = 0.f; sC[threadIdx.x] = 0.f; }
    __syncthreads();

    const int base = blockIdx.x * 2048;           // 2048 | NN so one batch per block
    const int b = base >> 18;                     // i / NN
#pragma unroll
    for (int j = 0; j < 2048; j += 256) {
        int i = base + j + threadIdx.x;
        if (mask[i]) {
            int g = grp[i];
            atomicAdd(&sP[g], pp[i * 3 + 2]);
            atomicAdd(&sT[g], tp[i * 3 + 2]);
            atomicAdd(&sC[g], 1.0f);
        }
    }
    __syncthreads();
    if (threadIdx.x < GG) {
        float c = sC[threadIdx.x];
        if (c != 0.0f) {
            int e = b * GG + threadIdx.x;
            atomicAdd(&ws[e], sP[threadIdx.x]);
            atomicAdd(&ws[NBG + e], sT[threadIdx.x]);
            atomicAdd(&ws[2 * NBG + e], c);
        }
    }
}

// ---- Kernel 2: finalize inverse safe means + total valid count. 1 block x 512 thr
__global__ __launch_bounds__(512) void k_groups_final(float* __restrict__ ws) {
    __shared__ float red[NBG];
    int j = threadIdx.x;
    float c = ws[2 * NBG + j];
    float mP = (c > 0.f) ? (ws[j] / fmaxf(c, 1.f)) : 1.0f;
    float mT = (c > 0.f) ? (ws[NBG + j] / fmaxf(c, 1.f)) : 1.0f;
    ws[3 * NBG + j] = 1.0f / fmaxf(fabsf(mP), 1e-6f);
    ws[4 * NBG + j] = 1.0f / fmaxf(fabsf(mT), 1e-6f);
    red[j] = c;
    __syncthreads();
    for (int s = 256; s > 0; s >>= 1) {
        if (j < s) red[j] += red[j + s];
        __syncthreads();
    }
    if (j == 0) ws[5 * NBG] = red[0];
}

// ---- Kernel 3: main loss pass. 2048 blocks x 256 thr, chunk=1024. NO global atomics.
__global__ __launch_bounds__(256) void k_loss(const float* __restrict__ pp,
                                              const float* __restrict__ tp,
                                              const float* __restrict__ p2,
                                              const float* __restrict__ t2,
                                              const float* __restrict__ pv,
                                              const float* __restrict__ tv,
                                              const float* __restrict__ pd,
                                              const float* __restrict__ td,
                                              const float* __restrict__ pn,
                                              const float* __restrict__ tn,
                                              const float* __restrict__ cf,
                                              const int* __restrict__ mask,
                                              const int* __restrict__ grp,
                                              float* __restrict__ ws) {
    const float* invP = ws + 3 * NBG;
    const float* invT = ws + 4 * NBG;

    float s3d = 0.f, s2 = 0.f, sv = 0.f, sd = 0.f, sn = 0.f, sc = 0.f;

    const int base = blockIdx.x * 1024;
#pragma unroll
    for (int j = 0; j < 1024; j += 256) {
        int i = base + j + threadIdx.x;
        float w = (float)mask[i];                 // branchless: 0/1 weight
        int e = ((i >> 18) << 6) | grp[i];
        float iP = invP[e], iT = invT[e];
        int i3 = i * 3;
        int i2 = i * 2;

        // L_3D: normalize by group mean depth, log-transform, L1
        float t3 = 0.f;
#pragma unroll
        for (int k = 0; k < 3; k++) {
            float a = pp[i3 + k] * iP;
            float b2 = tp[i3 + k] * iT;
            float la = copysignf(log1pf(fabsf(a)), a);
            float lb = copysignf(log1pf(fabsf(b2)), b2);
            t3 += fabsf(la - lb);
        }
        s3d += w * t3;
        // L_2D
        s2 += w * (fabsf(p2[i2] - t2[i2]) + fabsf(p2[i2 + 1] - t2[i2 + 1]));
        // L_vis (BCE with logits)
        {
            float x = pv[i], t = tv[i];
            sv += w * (fmaxf(x, 0.f) - x * t + log1pf(expf(-fabsf(x))));
        }
        // L_disp
        sd += w * (fabsf(pd[i3] - td[i3]) + fabsf(pd[i3 + 1] - td[i3 + 1]) + fabsf(pd[i3 + 2] - td[i3 + 2]));
        // L_normal: 1 - cos
        {
            float ax = pn[i3], ay = pn[i3 + 1], az = pn[i3 + 2];
            float bx = tn[i3], by = tn[i3 + 1], bz = tn[i3 + 2];
            float na = fmaxf(sqrtf(ax * ax + ay * ay + az * az), 1e-12f);
            float nb = fmaxf(sqrtf(bx * bx + by * by + bz * bz), 1e-12f);
            sn += w * (1.0f - (ax * bx + ay * by + az * bz) / (na * nb));
        }
        // L_conf
        sc += w * cf[i];
    }

    // block reduction -> one non-atomic write per (block, term)
    __shared__ float sred[4][6];
    float vals[6] = {s3d, s2, sv, sd, sn, sc};
    int wid = threadIdx.x >> 6, lane = threadIdx.x & 63;
#pragma unroll
    for (int k = 0; k < 6; k++) {
        float r = wredf(vals[k]);
        if (lane == 0) sred[wid][k] = r;
    }
    __syncthreads();
    if (threadIdx.x < 6) {
        float t = sred[0][threadIdx.x] + sred[1][threadIdx.x]
                + sred[2][threadIdx.x] + sred[3][threadIdx.x];
        ws[PART_F + threadIdx.x * NBLK + blockIdx.x] = t;
    }
}

// ---- Kernel 4: final reduce (2048 partials x 6) + combine. 1 block x 256 thr
__global__ __launch_bounds__(256) void k_final(const float* __restrict__ ws,
                                               float* __restrict__ out) {
    const float* part = ws + PART_F;
    double loc[6] = {0, 0, 0, 0, 0, 0};
    for (int j = threadIdx.x; j < NBLK; j += 256) {
#pragma unroll
        for (int k = 0; k < 6; k++) loc[k] += (double)part[k * NBLK + j];
    }
    __shared__ double dred[4][6];
    int wid = threadIdx.x >> 6, lane = threadIdx.x & 63;
#pragma unroll
    for (int k = 0; k < 6; k++) {
        double v = loc[k];
#pragma unroll
        for (int o = 32; o > 0; o >>= 1) v += __shfl_down(v, o, 64);
        if (lane == 0) dred[wid][k] = v;
    }
    __syncthreads();
    if (threadIdx.x == 0) {
        double a[6];
#pragma unroll
        for (int k = 0; k < 6; k++)
            a[k] = dred[0][k] + dred[1][k] + dred[2][k] + dred[3][k];
        double nv = (double)ws[5 * NBG];
        double d1 = nv + 1e-6;
        double d3 = 3.0 * nv + 1e-6;
        double l3d   = a[0] / d3;
        double l2d   = a[1] / (2.0 * nv + 1e-6);
        double lvis  = a[2] / d1;
        double ldisp = a[3] / d3;   // disp is (B,N,3): mask broadcasts to 3 channels
        double lnorm = a[4] / d1;
        double lconf = a[5] / d1;
        out[0] = (float)(l3d + 0.1 * (l2d + lvis + ldisp) + 0.5 * lnorm + 0.2 * lconf);
    }
}

extern "C" void kernel_launch(void* const* d_in, const int* in_sizes, int n_in,
                              void* d_out, int out_size, void* d_ws, size_t ws_size,
                              hipStream_t stream) {
    const float* pp = (const float*)d_in[0];
    const float* tp = (const float*)d_in[1];
    const float* p2 = (const float*)d_in[2];
    const float* t2 = (const float*)d_in[3];
    const float* pv = (const float*)d_in[4];
    const float* tv = (const float*)d_in[5];
    const float* pd = (const float*)d_in[6];
    const float* td = (const float*)d_in[7];
    const float* pn = (const float*)d_in[8];
    const float* tn = (const float*)d_in[9];
    const float* cf = (const float*)d_in[10];
    const int* mask = (const int*)d_in[11];
    const int* grp  = (const int*)d_in[12];
    float* ws = (float*)d_ws;
    float* out = (float*)d_out;

    hipMemsetAsync(d_ws, 0, WS_ZERO_BYTES, stream);
    k_group<<<TOT / 2048, 256, 0, stream>>>(pp, tp, mask, grp, ws);
    k_groups_final<<<1, NBG, 0, stream>>>(ws);
    k_loss<<<NBLK, 256, 0, stream>>>(pp, tp, p2, t2, pv, tv, pd, td, pn, tn, cf, mask, grp, ws);
    k_final<<<1, 256, 0, stream>>>(ws, out);
}

// Round 5
// 76.063 us; speedup vs baseline: 8.4443x; 1.0886x over previous
//
#include <hip/hip_runtime.h>
#include <math.h>

#define BB  8
#define NN  262144
#define GG  64
#define NBG (BB * GG)      // 512
#define TOT (BB * NN)      // 2097152
#define NBLK 2048          // k_loss blocks (256 thr x 4 pts = 1024 pts/block)

// ws float layout:
//   [0    ..  512) zsumP
//   [512  .. 1024) zsumT
//   [1024 .. 1536) cnt
//   [1536 .. 2560) interleaved (invP,invT) pairs: [1536+2e], [1536+2e+1]
//   [2560]         nvalid
//   [4096 .. 4096+6*2048) per-block partials, transposed: partials[k*2048+blk]
#define PAIR_F (3 * NBG)
#define PART_F 4096
#define WS_ZERO_BYTES (3 * NBG * 4)

#define LN2   0.6931471805599453f
#define LOG2E 1.4426950408889634f

// HW transcendentals via amdgcn builtins (avoid glibc __exp2f/__log2f name clash)
__device__ __forceinline__ float fexp2(float x) { return __builtin_amdgcn_exp2f(x); }  // 2^x
__device__ __forceinline__ float flog2(float x) { return __builtin_amdgcn_logf(x); }   // log2(x)

__device__ __forceinline__ float wredf(float v) {
#pragma unroll
    for (int o = 32; o > 0; o >>= 1) v += __shfl_down(v, o, 64);
    return v;
}

// fast log1p for x >= 0
__device__ __forceinline__ float flog1p(float x) {
    return flog2(1.0f + x) * LN2;
}

// ---- Kernel 1: per-(b,g) z sums + counts. 2048 blocks x 256 thr, 4 pts/thr
__global__ __launch_bounds__(256) void k_group(const float* __restrict__ pp,
                                               const float* __restrict__ tp,
                                               const int* __restrict__ mask,
                                               const int* __restrict__ grp,
                                               float* __restrict__ ws) {
    __shared__ float sP[GG], sT[GG], sC[GG];
    if (threadIdx.x < GG) { sP[threadIdx.x] = 0.f; sT[threadIdx.x] = 0.f; sC[threadIdx.x] = 0.f; }
    __syncthreads();

    const int t = blockIdx.x * 256 + threadIdx.x;
    const int p0 = t << 2;
    const int b = p0 >> 18;                      // 1024 pts/block, 256 blocks/batch

    const int4 M  = *(const int4*)(mask + p0);
    const int4 Gp = *(const int4*)(grp + p0);
    const float4* A = (const float4*)(pp + p0 * 3);
    const float4* Bv = (const float4*)(tp + p0 * 3);
    float4 a0 = A[0], a1 = A[1], a2 = A[2];
    float4 b0 = Bv[0], b1 = Bv[1], b2 = Bv[2];

    const int   Ms[4] = {M.x, M.y, M.z, M.w};
    const int   Gs[4] = {Gp.x, Gp.y, Gp.z, Gp.w};
    const float zP[4] = {a0.z, a1.y, a2.x, a2.w};
    const float zT[4] = {b0.z, b1.y, b2.x, b2.w};

#pragma unroll
    for (int k = 0; k < 4; k++) {
        if (Ms[k]) {
            atomicAdd(&sP[Gs[k]], zP[k]);
            atomicAdd(&sT[Gs[k]], zT[k]);
            atomicAdd(&sC[Gs[k]], 1.0f);
        }
    }
    __syncthreads();
    if (threadIdx.x < GG) {
        float c = sC[threadIdx.x];
        if (c != 0.0f) {
            int e = b * GG + threadIdx.x;
            atomicAdd(&ws[e], sP[threadIdx.x]);
            atomicAdd(&ws[NBG + e], sT[threadIdx.x]);
            atomicAdd(&ws[2 * NBG + e], c);
        }
    }
}

// ---- Kernel 2: finalize interleaved inverse safe means + total valid count
__global__ __launch_bounds__(512) void k_groups_final(float* __restrict__ ws) {
    __shared__ float red[NBG];
    int j = threadIdx.x;
    float c = ws[2 * NBG + j];
    float mP = (c > 0.f) ? (ws[j] / fmaxf(c, 1.f)) : 1.0f;
    float mT = (c > 0.f) ? (ws[NBG + j] / fmaxf(c, 1.f)) : 1.0f;
    ws[PAIR_F + 2 * j]     = 1.0f / fmaxf(fabsf(mP), 1e-6f);
    ws[PAIR_F + 2 * j + 1] = 1.0f / fmaxf(fabsf(mT), 1e-6f);
    red[j] = c;
    __syncthreads();
    for (int s = 256; s > 0; s >>= 1) {
        if (j < s) red[j] += red[j + s];
        __syncthreads();
    }
    if (j == 0) ws[5 * NBG] = red[0];
}

// ---- Kernel 3: main loss pass. 2048 blocks x 256 thr, 4 pts/thr, float4 loads
__global__ __launch_bounds__(256) void k_loss(const float* __restrict__ pp,
                                              const float* __restrict__ tp,
                                              const float* __restrict__ p2,
                                              const float* __restrict__ t2,
                                              const float* __restrict__ pv,
                                              const float* __restrict__ tv,
                                              const float* __restrict__ pd,
                                              const float* __restrict__ td,
                                              const float* __restrict__ pn,
                                              const float* __restrict__ tn,
                                              const float* __restrict__ cf,
                                              const int* __restrict__ mask,
                                              const int* __restrict__ grp,
                                              float* __restrict__ ws) {
    const float* pairs = ws + PAIR_F;

    const int t = blockIdx.x * 256 + threadIdx.x;
    const int p0 = t << 2;
    const int bb6 = (p0 >> 18) << 6;

    // --- weights + group scale pairs
    const int4 M  = *(const int4*)(mask + p0);
    const int4 Gp = *(const int4*)(grp + p0);
    const int Ms[4] = {M.x, M.y, M.z, M.w};
    const int Gs[4] = {Gp.x, Gp.y, Gp.z, Gp.w};
    float w[4], iP[4], iT[4];
#pragma unroll
    for (int k = 0; k < 4; k++) {
        w[k] = (float)Ms[k];
        float2 pr = *(const float2*)(pairs + 2 * (bb6 | Gs[k]));
        iP[k] = pr.x; iT[k] = pr.y;
    }

    float s3d = 0.f, s2 = 0.f, sv = 0.f, sd = 0.f, sn = 0.f, sc = 0.f;

    // --- L_3D
    {
        const float4* A = (const float4*)(pp + p0 * 3);
        const float4* Bv = (const float4*)(tp + p0 * 3);
        float P[12], T[12];
        *(float4*)&P[0] = A[0]; *(float4*)&P[4] = A[1]; *(float4*)&P[8] = A[2];
        *(float4*)&T[0] = Bv[0]; *(float4*)&T[4] = Bv[1]; *(float4*)&T[8] = Bv[2];
#pragma unroll
        for (int k = 0; k < 4; k++) {
            float acc = 0.f;
#pragma unroll
            for (int c = 0; c < 3; c++) {
                float a = P[3 * k + c] * iP[k];
                float b = T[3 * k + c] * iT[k];
                float la = copysignf(flog1p(fabsf(a)), a);
                float lb = copysignf(flog1p(fabsf(b)), b);
                acc += fabsf(la - lb);
            }
            s3d += w[k] * acc;
        }
    }
    // --- L_2D
    {
        const float4* A = (const float4*)(p2 + p0 * 2);
        const float4* Bv = (const float4*)(t2 + p0 * 2);
        float P[8], T[8];
        *(float4*)&P[0] = A[0]; *(float4*)&P[4] = A[1];
        *(float4*)&T[0] = Bv[0]; *(float4*)&T[4] = Bv[1];
#pragma unroll
        for (int k = 0; k < 4; k++)
            s2 += w[k] * (fabsf(P[2 * k] - T[2 * k]) + fabsf(P[2 * k + 1] - T[2 * k + 1]));
    }
    // --- L_vis (BCE with logits), L_conf
    {
        float4 X = *(const float4*)(pv + p0);
        float4 Tg = *(const float4*)(tv + p0);
        float4 C = *(const float4*)(cf + p0);
        const float xs[4] = {X.x, X.y, X.z, X.w};
        const float ts[4] = {Tg.x, Tg.y, Tg.z, Tg.w};
        const float cs[4] = {C.x, C.y, C.z, C.w};
#pragma unroll
        for (int k = 0; k < 4; k++) {
            float x = xs[k];
            float soft = flog2(1.0f + fexp2(-fabsf(x) * LOG2E)) * LN2;
            sv += w[k] * (fmaxf(x, 0.f) - x * ts[k] + soft);
            sc += w[k] * cs[k];
        }
    }
    // --- L_disp
    {
        const float4* A = (const float4*)(pd + p0 * 3);
        const float4* Bv = (const float4*)(td + p0 * 3);
        float P[12], T[12];
        *(float4*)&P[0] = A[0]; *(float4*)&P[4] = A[1]; *(float4*)&P[8] = A[2];
        *(float4*)&T[0] = Bv[0]; *(float4*)&T[4] = Bv[1]; *(float4*)&T[8] = Bv[2];
#pragma unroll
        for (int k = 0; k < 4; k++) {
            float acc = 0.f;
#pragma unroll
            for (int c = 0; c < 3; c++) acc += fabsf(P[3 * k + c] - T[3 * k + c]);
            sd += w[k] * acc;
        }
    }
    // --- L_normal
    {
        const float4* A = (const float4*)(pn + p0 * 3);
        const float4* Bv = (const float4*)(tn + p0 * 3);
        float P[12], T[12];
        *(float4*)&P[0] = A[0]; *(float4*)&P[4] = A[1]; *(float4*)&P[8] = A[2];
        *(float4*)&T[0] = Bv[0]; *(float4*)&T[4] = Bv[1]; *(float4*)&T[8] = Bv[2];
#pragma unroll
        for (int k = 0; k < 4; k++) {
            float ax = P[3 * k], ay = P[3 * k + 1], az = P[3 * k + 2];
            float bx = T[3 * k], by = T[3 * k + 1], bz = T[3 * k + 2];
            float na = fmaf(ax, ax, fmaf(ay, ay, az * az));
            float nb = fmaf(bx, bx, fmaf(by, by, bz * bz));
            float dot = fmaf(ax, bx, fmaf(ay, by, az * bz));
            float r = __frsqrt_rn(fmaxf(na, 1e-24f)) * __frsqrt_rn(fmaxf(nb, 1e-24f));
            sn += w[k] * (1.0f - dot * r);
        }
    }

    // block reduction -> one non-atomic write per (block, term)
    __shared__ float sred[4][6];
    float vals[6] = {s3d, s2, sv, sd, sn, sc};
    int wid = threadIdx.x >> 6, lane = threadIdx.x & 63;
#pragma unroll
    for (int k = 0; k < 6; k++) {
        float r = wredf(vals[k]);
        if (lane == 0) sred[wid][k] = r;
    }
    __syncthreads();
    if (threadIdx.x < 6) {
        float tt = sred[0][threadIdx.x] + sred[1][threadIdx.x]
                 + sred[2][threadIdx.x] + sred[3][threadIdx.x];
        ws[PART_F + threadIdx.x * NBLK + blockIdx.x] = tt;
    }
}

// ---- Kernel 4: final reduce (2048 partials x 6) + combine. 1 block x 256 thr
__global__ __launch_bounds__(256) void k_final(const float* __restrict__ ws,
                                               float* __restrict__ out) {
    const float* part = ws + PART_F;
    double loc[6] = {0, 0, 0, 0, 0, 0};
    for (int j = threadIdx.x; j < NBLK; j += 256) {
#pragma unroll
        for (int k = 0; k < 6; k++) loc[k] += (double)part[k * NBLK + j];
    }
    __shared__ double dred[4][6];
    int wid = threadIdx.x >> 6, lane = threadIdx.x & 63;
#pragma unroll
    for (int k = 0; k < 6; k++) {
        double v = loc[k];
#pragma unroll
        for (int o = 32; o > 0; o >>= 1) v += __shfl_down(v, o, 64);
        if (lane == 0) dred[wid][k] = v;
    }
    __syncthreads();
    if (threadIdx.x == 0) {
        double a[6];
#pragma unroll
        for (int k = 0; k < 6; k++)
            a[k] = dred[0][k] + dred[1][k] + dred[2][k] + dred[3][k];
        double nv = (double)ws[5 * NBG];
        double d1 = nv + 1e-6;
        double d3 = 3.0 * nv + 1e-6;
        double l3d   = a[0] / d3;
        double l2d   = a[1] / (2.0 * nv + 1e-6);
        double lvis  = a[2] / d1;
        double ldisp = a[3] / d3;   // disp is (B,N,3): mask broadcasts to 3 channels
        double lnorm = a[4] / d1;
        double lconf = a[5] / d1;
        out[0] = (float)(l3d + 0.1 * (l2d + lvis + ldisp) + 0.5 * lnorm + 0.2 * lconf);
    }
}

extern "C" void kernel_launch(void* const* d_in, const int* in_sizes, int n_in,
                              void* d_out, int out_size, void* d_ws, size_t ws_size,
                              hipStream_t stream) {
    const float* pp = (const float*)d_in[0];
    const float* tp = (const float*)d_in[1];
    const float* p2 = (const float*)d_in[2];
    const float* t2 = (const float*)d_in[3];
    const float* pv = (const float*)d_in[4];
    const float* tv = (const float*)d_in[5];
    const float* pd = (const float*)d_in[6];
    const float* td = (const float*)d_in[7];
    const float* pn = (const float*)d_in[8];
    const float* tn = (const float*)d_in[9];
    const float* cf = (const float*)d_in[10];
    const int* mask = (const int*)d_in[11];
    const int* grp  = (const int*)d_in[12];
    float* ws = (float*)d_ws;
    float* out = (float*)d_out;

    (void)hipMemsetAsync(d_ws, 0, WS_ZERO_BYTES, stream);
    k_group<<<TOT / 1024, 256, 0, stream>>>(pp, tp, mask, grp, ws);
    k_groups_final<<<1, NBG, 0, stream>>>(ws);
    k_loss<<<NBLK, 256, 0, stream>>>(pp, tp, p2, t2, pv, tv, pd, td, pn, tn, cf, mask, grp, ws);
    k_final<<<1, 256, 0, stream>>>(ws, out);
}